// Round 2
// baseline (591.865 us; speedup 1.0000x reference)
//
#include <hip/hip_runtime.h>
#include <hip/hip_bf16.h>

using bf16 = __hip_bfloat16;

#define BATCH 16
#define NNODE 2000
#define DIM   128
#define ODIM  64
#define NLAYER 3
#define BN    (BATCH*NNODE)   // 32000
#define NP1   (NNODE+1)       // 2001
#define CHK   16              // chunks per batch
#define CKS   125             // chunk size (16*125 = 2000)

// converted-input element offsets inside cvt buffer
#define OFF_COORDS 0
#define OFF_EW0    64000
#define OFF_EB0    64256
#define OFF_EW1    64384
#define OFF_EB1    80768
#define OFF_GW     80896
#define OFF_GA1    130048
#define OFF_GA2    130432
#define OFF_PW     130816
#define OFF_PB     139008
#define CVT_TOT    139072

// ------------- dtype sniff: bf16 storage => even halfwords all have sane exponent ----
__global__ void sniff_k(const unsigned short* __restrict__ raw, float* __restrict__ flag)
{
    __shared__ int cnt[256];
    int t = threadIdx.x, c = 0;
    for (int k = t; k < 2048; k += 256){
        unsigned short u = raw[2*k];          // even halfwords (8 KB touched, safe)
        int e = (u >> 7) & 0xFF;
        if (e >= 100 && e <= 140) ++c;
    }
    cnt[t] = c;
    __syncthreads();
    for (int s = 128; s; s >>= 1){ if (t < s) cnt[t] += cnt[t+s]; __syncthreads(); }
    if (t == 0) flag[0] = (cnt[0] >= 1800) ? 1.0f : 0.0f;   // 1 => bf16 storage
}

// ------------- convert any input to fp32 scratch ----------------------------------
__global__ void convert_k(const void* __restrict__ src, float* __restrict__ dst, int n,
                          const float* __restrict__ flag)
{
    int i = blockIdx.x*256 + threadIdx.x;
    if (i >= n) return;
    if (flag[0] != 0.0f) dst[i] = __bfloat162float(((const bf16*)src)[i]);
    else                 dst[i] = ((const float*)src)[i];
}

// ------------- encoder layer 0: h0 = relu(coords @ w0 + b0) ------------------------
__global__ void enc0_k(const float* __restrict__ cvt, float* __restrict__ h0)
{
    int gid  = blockIdx.x*256 + threadIdx.x;       // BN*DIM threads
    int node = gid >> 7, d = gid & 127;
    const float* coords = cvt + OFF_COORDS;
    const float* w0     = cvt + OFF_EW0;
    const float* b0     = cvt + OFF_EB0;
    float c0 = coords[node*2+0], c1 = coords[node*2+1];
    float v  = fmaf(c0, w0[d], fmaf(c1, w0[DIM+d], b0[d]));
    h0[gid]  = v > 0.f ? v : 0.f;
}

// ------------- fp32 GEMM: out[M,NCOLS] = A[M,128] @ W[128,NCOLS] (+bias) -----------
// block 256, tile 32 rows x 64 cols; grid = (M/32, NCOLS/64); LDS 48 KB
template<int NCOLS>
__global__ __launch_bounds__(256) void gemm32_k(const float* __restrict__ A,
    const float* __restrict__ W, const float* __restrict__ bias, float* __restrict__ out)
{
    __shared__ __align__(16) float sW[128*64];   // [k][cc] 32 KB
    __shared__ __align__(16) float sA[32*128];   // [r][k]  16 KB
    const int rt = blockIdx.x, cb = blockIdx.y, tid = threadIdx.x;

    for (int e = tid; e < 128*64; e += 256){
        int k = e >> 6, cc = e & 63;
        sW[e] = W[k*NCOLS + cb*64 + cc];
    }
    const float4* Ab = (const float4*)(A + (size_t)rt*32*128);
    float4* sA4 = (float4*)sA;
    for (int q = tid; q < 32*32; q += 256) sA4[q] = Ab[q];
    __syncthreads();

    const int cq = tid & 15, rr = tid >> 4;      // cols cq*4.., rows rr & rr+16
    float4 acc0 = make_float4(0.f,0.f,0.f,0.f);
    float4 acc1 = make_float4(0.f,0.f,0.f,0.f);
    for (int kq = 0; kq < 32; ++kq){
        float4 w0 = *(float4*)&sW[(kq*4+0)*64 + cq*4];
        float4 w1 = *(float4*)&sW[(kq*4+1)*64 + cq*4];
        float4 w2 = *(float4*)&sW[(kq*4+2)*64 + cq*4];
        float4 w3 = *(float4*)&sW[(kq*4+3)*64 + cq*4];
        float4 a0 = *(float4*)&sA[rr*128 + kq*4];
        float4 a1 = *(float4*)&sA[(rr+16)*128 + kq*4];
        acc0.x = fmaf(a0.x,w0.x, fmaf(a0.y,w1.x, fmaf(a0.z,w2.x, fmaf(a0.w,w3.x, acc0.x))));
        acc0.y = fmaf(a0.x,w0.y, fmaf(a0.y,w1.y, fmaf(a0.z,w2.y, fmaf(a0.w,w3.y, acc0.y))));
        acc0.z = fmaf(a0.x,w0.z, fmaf(a0.y,w1.z, fmaf(a0.z,w2.z, fmaf(a0.w,w3.z, acc0.z))));
        acc0.w = fmaf(a0.x,w0.w, fmaf(a0.y,w1.w, fmaf(a0.z,w2.w, fmaf(a0.w,w3.w, acc0.w))));
        acc1.x = fmaf(a1.x,w0.x, fmaf(a1.y,w1.x, fmaf(a1.z,w2.x, fmaf(a1.w,w3.x, acc1.x))));
        acc1.y = fmaf(a1.x,w0.y, fmaf(a1.y,w1.y, fmaf(a1.z,w2.y, fmaf(a1.w,w3.y, acc1.y))));
        acc1.z = fmaf(a1.x,w0.z, fmaf(a1.y,w1.z, fmaf(a1.z,w2.z, fmaf(a1.w,w3.z, acc1.z))));
        acc1.w = fmaf(a1.x,w0.w, fmaf(a1.y,w1.w, fmaf(a1.z,w2.w, fmaf(a1.w,w3.w, acc1.w))));
    }
    const int col0 = cb*64 + cq*4;
    float b0=0.f,b1=0.f,b2=0.f,b3=0.f;
    if (bias){ b0=bias[col0]; b1=bias[col0+1]; b2=bias[col0+2]; b3=bias[col0+3]; }
    int r0 = rt*32 + rr;
    *(float4*)&out[(size_t)r0*NCOLS + col0]      = make_float4(acc0.x+b0, acc0.y+b1, acc0.z+b2, acc0.w+b3);
    *(float4*)&out[(size_t)(r0+16)*NCOLS + col0] = make_float4(acc1.x+b0, acc1.y+b1, acc1.z+b2, acc1.w+b3);
}

// ------------- final projection GEMM, output dtype per flag ------------------------
__global__ __launch_bounds__(256) void gemmout_k(const float* __restrict__ A,
    const float* __restrict__ W, const float* __restrict__ bias,
    void* __restrict__ outp, const float* __restrict__ flag)
{
    __shared__ __align__(16) float sW[128*64];
    __shared__ __align__(16) float sA[32*128];
    const int rt = blockIdx.x, tid = threadIdx.x;
    for (int e = tid; e < 128*64; e += 256){
        int k = e >> 6, cc = e & 63;
        sW[e] = W[k*ODIM + cc];
    }
    const float4* Ab = (const float4*)(A + (size_t)rt*32*128);
    float4* sA4 = (float4*)sA;
    for (int q = tid; q < 32*32; q += 256) sA4[q] = Ab[q];
    __syncthreads();

    const int cq = tid & 15, rr = tid >> 4;
    float4 acc0 = make_float4(0.f,0.f,0.f,0.f);
    float4 acc1 = make_float4(0.f,0.f,0.f,0.f);
    for (int kq = 0; kq < 32; ++kq){
        float4 w0 = *(float4*)&sW[(kq*4+0)*64 + cq*4];
        float4 w1 = *(float4*)&sW[(kq*4+1)*64 + cq*4];
        float4 w2 = *(float4*)&sW[(kq*4+2)*64 + cq*4];
        float4 w3 = *(float4*)&sW[(kq*4+3)*64 + cq*4];
        float4 a0 = *(float4*)&sA[rr*128 + kq*4];
        float4 a1 = *(float4*)&sA[(rr+16)*128 + kq*4];
        acc0.x = fmaf(a0.x,w0.x, fmaf(a0.y,w1.x, fmaf(a0.z,w2.x, fmaf(a0.w,w3.x, acc0.x))));
        acc0.y = fmaf(a0.x,w0.y, fmaf(a0.y,w1.y, fmaf(a0.z,w2.y, fmaf(a0.w,w3.y, acc0.y))));
        acc0.z = fmaf(a0.x,w0.z, fmaf(a0.y,w1.z, fmaf(a0.z,w2.z, fmaf(a0.w,w3.z, acc0.z))));
        acc0.w = fmaf(a0.x,w0.w, fmaf(a0.y,w1.w, fmaf(a0.z,w2.w, fmaf(a0.w,w3.w, acc0.w))));
        acc1.x = fmaf(a1.x,w0.x, fmaf(a1.y,w1.x, fmaf(a1.z,w2.x, fmaf(a1.w,w3.x, acc1.x))));
        acc1.y = fmaf(a1.x,w0.y, fmaf(a1.y,w1.y, fmaf(a1.z,w2.y, fmaf(a1.w,w3.y, acc1.y))));
        acc1.z = fmaf(a1.x,w0.z, fmaf(a1.y,w1.z, fmaf(a1.z,w2.z, fmaf(a1.w,w3.z, acc1.z))));
        acc1.w = fmaf(a1.x,w0.w, fmaf(a1.y,w1.w, fmaf(a1.z,w2.w, fmaf(a1.w,w3.w, acc1.w))));
    }
    const int col0 = cq*4;
    float b0=bias[col0], b1=bias[col0+1], b2=bias[col0+2], b3=bias[col0+3];
    float o0[4] = {acc0.x+b0, acc0.y+b1, acc0.z+b2, acc0.w+b3};
    float o1[4] = {acc1.x+b0, acc1.y+b1, acc1.z+b2, acc1.w+b3};
    int r0 = rt*32 + rr;
    size_t p0 = (size_t)r0*ODIM + col0, p1 = (size_t)(r0+16)*ODIM + col0;
    if (flag[0] != 0.0f){
        bf16* ob = (bf16*)outp;
        #pragma unroll
        for (int i = 0; i < 4; ++i){ ob[p0+i] = __float2bfloat16(o0[i]); ob[p1+i] = __float2bfloat16(o1[i]); }
    } else {
        float* of = (float*)outp;
        *(float4*)&of[p0] = make_float4(o0[0],o0[1],o0[2],o0[3]);
        *(float4*)&of[p1] = make_float4(o1[0],o1[1],o1[2],o1[3]);
    }
}

// ------------- e1 = Wh @ a1, e2 = Wh @ a2 (wave per row) --------------------------
__global__ void e1e2_k(const float* __restrict__ Wh, const float* __restrict__ cvt, int l,
                       float* __restrict__ e1, float* __restrict__ e2)
{
    const float* a1f = cvt + OFF_GA1 + l*DIM;
    const float* a2f = cvt + OFF_GA2 + l*DIM;
    int lane = threadIdx.x & 63;
    int row  = blockIdx.x*4 + (threadIdx.x >> 6);
    const float* w = Wh + (size_t)row*DIM;
    float wlo = w[lane], whi = w[lane+64];
    float s1 = fmaf(wlo, a1f[lane], whi * a1f[lane+64]);
    float s2 = fmaf(wlo, a2f[lane], whi * a2f[lane+64]);
    #pragma unroll
    for (int off = 32; off; off >>= 1){ s1 += __shfl_down(s1, off); s2 += __shfl_down(s2, off); }
    if (lane == 0){ e1[row] = s1; e2[row] = s2; }
}

// ------------- per-batch bitonic sort of e2 (2000 -> pad 2048) --------------------
__global__ void sort_k(const float* __restrict__ e2, float* __restrict__ e2s, int* __restrict__ sidx,
                       float* __restrict__ wp, float* __restrict__ wn, float* __restrict__ e2m)
{
    __shared__ float v[2048];
    __shared__ int  ix[2048];
    const int b = blockIdx.x, t = threadIdx.x;   // 1024 threads
    for (int i = t; i < 2048; i += 1024){
        v[i]  = (i < NNODE) ? e2[b*NNODE + i] : 3.0e38f;
        ix[i] = i;
    }
    __syncthreads();
    for (int size = 2; size <= 2048; size <<= 1){
        for (int stride = size >> 1; stride > 0; stride >>= 1){
            int i = 2*t - (t & (stride-1));
            int j = i + stride;
            bool asc = ((i & size) == 0);
            float vi = v[i], vj = v[j];
            bool sw = asc ? (vi > vj) : (vi < vj);
            if (sw){ v[i]=vj; v[j]=vi; int tm=ix[i]; ix[i]=ix[j]; ix[j]=tm; }
            __syncthreads();
        }
    }
    float mx = v[NNODE-1];   // pads sort to 2000..2047, so this is the true max
    for (int i = t; i < NNODE; i += 1024){
        float val = v[i];
        e2s [b*NNODE+i] = val;
        sidx[b*NNODE+i] = ix[i];
        wp  [b*NNODE+i] = __expf(val - mx);          // <= 1
        wn  [b*NNODE+i] = __expf(0.2f*(val - mx));   // <= 1
    }
    if (t == 0) e2m[b] = mx;
}

// ------------- pass A: per-chunk partial sums (vector[D] + scalar) ----------------
__global__ void passA_k(const float* __restrict__ Wh, const int* __restrict__ sidx,
    const float* __restrict__ wp, const float* __restrict__ wn,
    float* __restrict__ chunkP, float* __restrict__ chunkN,
    float* __restrict__ schunkP, float* __restrict__ schunkN)
{
    const int b = blockIdx.x >> 4, c = blockIdx.x & 15, d = threadIdx.x;  // 128 threads
    const int base = b*NNODE;
    float sp=0.f, sn=0.f, ssp=0.f, ssn=0.f;
    for (int r = c*CKS; r < c*CKS + CKS; ++r){
        int j = sidx[base + r];
        float whv = Wh[((size_t)base + j)*DIM + d];
        float wpv = wp[base + r], wnv = wn[base + r];
        sp = fmaf(wpv, whv, sp);  sn = fmaf(wnv, whv, sn);
        ssp += wpv;  ssn += wnv;
    }
    chunkP[(b*CHK+c)*DIM + d] = sp;
    chunkN[(b*CHK+c)*DIM + d] = sn;
    if (d == 0){ schunkP[b*CHK+c] = ssp; schunkN[b*CHK+c] = ssn; }
}

// ------------- pass C: suffix (pos) / prefix (neg) arrays over sorted order -------
__global__ void passC_k(const float* __restrict__ Wh, const int* __restrict__ sidx,
    const float* __restrict__ wp, const float* __restrict__ wn,
    const float* __restrict__ chunkP, const float* __restrict__ chunkN,
    const float* __restrict__ schunkP, const float* __restrict__ schunkN,
    float* __restrict__ Ppos, float* __restrict__ Pneg,
    float* __restrict__ pposs, float* __restrict__ pnegs)
{
    const int b = blockIdx.x >> 4, c = blockIdx.x & 15, d = threadIdx.x;
    const int base = b*NNODE;
    const size_t pb = (size_t)b*NP1;
    float pos_off=0.f, neg_off=0.f, spos=0.f, sneg=0.f;
    for (int cc = c+1; cc < CHK; ++cc){ pos_off += chunkP[(b*CHK+cc)*DIM + d]; spos += schunkP[b*CHK+cc]; }
    for (int cc = 0;   cc < c;   ++cc){ neg_off += chunkN[(b*CHK+cc)*DIM + d]; sneg += schunkN[b*CHK+cc]; }
    const int r0 = c*CKS, r1 = r0 + CKS;

    if (c == CHK-1){
        Ppos[(pb + NNODE)*DIM + d] = 0.f;
        if (d == 0) pposs[pb + NNODE] = 0.f;
    }
    float pr = pos_off, spr = spos;                       // suffix sums, descending
    for (int r = r1-1; r >= r0; --r){
        int j = sidx[base + r];
        float whv = Wh[((size_t)base + j)*DIM + d];
        float wpv = wp[base + r];
        pr  = fmaf(wpv, whv, pr);
        spr += wpv;
        Ppos[(pb + r)*DIM + d] = pr;
        if (d == 0) pposs[pb + r] = spr;
    }
    float nr = neg_off, snr = sneg;                       // prefix sums (exclusive)
    for (int r = r0; r < r1; ++r){
        int j = sidx[base + r];
        float whv = Wh[((size_t)base + j)*DIM + d];
        float wnv = wn[base + r];
        Pneg[(pb + r)*DIM + d] = nr;
        if (d == 0) pnegs[pb + r] = snr;
        nr  = fmaf(wnv, whv, nr);
        snr += wnv;
    }
    if (c == CHK-1){
        Pneg[(pb + NNODE)*DIM + d] = nr;
        if (d == 0) pnegs[pb + NNODE] = snr;
    }
}

// ------------- output: h_i = relu((ps*Spos + ns*Sneg)/(ps*zpos + ns*zneg)) --------
__global__ void out_k(const float* __restrict__ e1, const float* __restrict__ e2s,
    const float* __restrict__ e2m, const float* __restrict__ Ppos, const float* __restrict__ Pneg,
    const float* __restrict__ pposs, const float* __restrict__ pnegs, float* __restrict__ h)
{
    const int row = blockIdx.x, d = threadIdx.x;   // 128 threads
    const int b = row / NNODE;
    float e1v = e1[row];
    float s = e1v + e2m[b];
    float m = (s >= 0.f) ? s : 0.2f*s;             // = max_j leaky(e1_i + e2_j)
    float ps = __expf(s - m);                      // <= 1
    float ns = __expf(0.2f*s - m);                 // <= 1
    const float* es = e2s + b*NNODE;
    float t = -e1v;
    int lo = 0, hi = NNODE;                        // first k with es[k] >= t
    while (lo < hi){ int mid = (lo+hi) >> 1; if (es[mid] < t) lo = mid+1; else hi = mid; }
    size_t kb = (size_t)b*NP1 + lo;
    float numer = ps*Ppos[kb*DIM + d] + ns*Pneg[kb*DIM + d];
    float Z     = ps*pposs[kb]        + ns*pnegs[kb];       // >= min(ps,ns)·1 > 0
    float q = numer / Z;
    // NaN-transparent relu: NaN propagates (diagnostic), negatives clamp to 0
    h[(size_t)row*DIM + d] = (q > 0.f) ? q : ((q == q) ? 0.f : q);
}

extern "C" void kernel_launch(void* const* d_in, const int* in_sizes, int n_in,
                              void* d_out, int out_size, void* d_ws, size_t ws_size,
                              hipStream_t stream)
{
    (void)in_sizes; (void)n_in; (void)out_size; (void)ws_size;

    float* f = (float*)d_ws;
    float* flag    = f;  f += 4;
    float* cvt     = f;  f += CVT_TOT;                 // 0.56 MB
    float* h       = f;  f += (size_t)BN*DIM;          // 16.4 MB
    float* Wh      = f;  f += (size_t)BN*DIM;          // 16.4 MB
    float* Ppos    = f;  f += (size_t)BATCH*NP1*DIM;   // 16.4 MB
    float* Pneg    = f;  f += (size_t)BATCH*NP1*DIM;   // 16.4 MB
    float* chunkP  = f;  f += BATCH*CHK*DIM;
    float* chunkN  = f;  f += BATCH*CHK*DIM;
    float* schunkP = f;  f += BATCH*CHK;
    float* schunkN = f;  f += BATCH*CHK;
    float* e1      = f;  f += BN;
    float* e2      = f;  f += BN;
    float* e2s     = f;  f += BN;
    float* wp      = f;  f += BN;
    float* wn      = f;  f += BN;
    float* pposs   = f;  f += BATCH*NP1;
    float* pnegs   = f;  f += BATCH*NP1;
    float* e2m     = f;  f += 16;
    int*   sidx    = (int*)f;

    // 1. dtype sniff + convert all inputs to fp32
    sniff_k<<<1, 256, 0, stream>>>((const unsigned short*)d_in[0], flag);
    static const int insz[10] = {64000,256,128,16384,128,49152,384,384,8192,64};
    static const int inoff[10] = {OFF_COORDS,OFF_EW0,OFF_EB0,OFF_EW1,OFF_EB1,
                                  OFF_GW,OFF_GA1,OFF_GA2,OFF_PW,OFF_PB};
    for (int i = 0; i < 10; ++i)
        convert_k<<<(insz[i]+255)/256, 256, 0, stream>>>(d_in[i], cvt + inoff[i], insz[i], flag);

    // 2. encoder: h0 = relu(coords@w0+b0) -> Wh buffer; h = h0@w1 + b1
    enc0_k<<<BN*DIM/256, 256, 0, stream>>>(cvt, Wh);
    gemm32_k<DIM><<<dim3(BN/32, 2), 256, 0, stream>>>(Wh, cvt + OFF_EW1, cvt + OFF_EB1, h);

    // 3. GAT layers (exact separable-softmax factorization)
    for (int l = 0; l < NLAYER; ++l){
        gemm32_k<DIM><<<dim3(BN/32, 2), 256, 0, stream>>>(h, cvt + OFF_GW + l*DIM*DIM, nullptr, Wh);
        e1e2_k<<<BN/4, 256, 0, stream>>>(Wh, cvt, l, e1, e2);
        sort_k<<<BATCH, 1024, 0, stream>>>(e2, e2s, sidx, wp, wn, e2m);
        passA_k<<<BATCH*CHK, DIM, 0, stream>>>(Wh, sidx, wp, wn, chunkP, chunkN, schunkP, schunkN);
        passC_k<<<BATCH*CHK, DIM, 0, stream>>>(Wh, sidx, wp, wn, chunkP, chunkN,
                                               schunkP, schunkN, Ppos, Pneg, pposs, pnegs);
        out_k<<<BN, DIM, 0, stream>>>(e1, e2s, e2m, Ppos, Pneg, pposs, pnegs, h);
    }

    // 4. projection, output dtype per flag
    gemmout_k<<<BN/32, 256, 0, stream>>>(h, cvt + OFF_PW, cvt + OFF_PB, d_out, flag);
}

// Round 3
// 559.342 us; speedup vs baseline: 1.0581x; 1.0581x over previous
//
#include <hip/hip_runtime.h>
#include <hip/hip_bf16.h>

using bf16 = __hip_bfloat16;

#define BATCH 16
#define NNODE 2000
#define DIM   128
#define ODIM  64
#define NLAYER 3
#define BN    (BATCH*NNODE)   // 32000
#define NP1   (NNODE+1)       // 2001
#define CHK   125             // chunks per batch
#define CKS   16              // chunk size (125*16 = 2000)

// converted-input element offsets inside cvt buffer
#define OFF_COORDS 0
#define OFF_EW0    64000
#define OFF_EB0    64256
#define OFF_EW1    64384
#define OFF_EB1    80768
#define OFF_GW     80896
#define OFF_GA1    130048
#define OFF_GA2    130432
#define OFF_PW     130816
#define OFF_PB     139008
#define CVT_TOT    139072

// ------------- dtype sniff: bf16 storage => even halfwords all have sane exponent ----
__global__ void sniff_k(const unsigned short* __restrict__ raw, float* __restrict__ flag)
{
    __shared__ int cnt[256];
    int t = threadIdx.x, c = 0;
    for (int k = t; k < 2048; k += 256){
        unsigned short u = raw[2*k];          // even halfwords (8 KB touched, safe)
        int e = (u >> 7) & 0xFF;
        if (e >= 100 && e <= 140) ++c;
    }
    cnt[t] = c;
    __syncthreads();
    for (int s = 128; s; s >>= 1){ if (t < s) cnt[t] += cnt[t+s]; __syncthreads(); }
    if (t == 0) flag[0] = (cnt[0] >= 1800) ? 1.0f : 0.0f;   // 1 => bf16 storage
}

// ------------- convert ALL inputs to fp32 scratch in one launch --------------------
struct InPtrs { const void* p[10]; };

__global__ void convert_all_k(InPtrs in, float* __restrict__ dst, const float* __restrict__ flag)
{
    const int off[11] = {OFF_COORDS,OFF_EW0,OFF_EB0,OFF_EW1,OFF_EB1,
                         OFF_GW,OFF_GA1,OFF_GA2,OFF_PW,OFF_PB,CVT_TOT};
    int i = blockIdx.x*256 + threadIdx.x;
    if (i >= CVT_TOT) return;
    int seg = 0;
    #pragma unroll
    for (int s = 1; s < 10; ++s) if (i >= off[s]) seg = s;
    int li = i - off[seg];
    if (flag[0] != 0.0f) dst[i] = __bfloat162float(((const bf16*)in.p[seg])[li]);
    else                 dst[i] = ((const float*)in.p[seg])[li];
}

// ------------- encoder layer 0: h0 = relu(coords @ w0 + b0) ------------------------
__global__ void enc0_k(const float* __restrict__ cvt, float* __restrict__ h0)
{
    int gid  = blockIdx.x*256 + threadIdx.x;       // BN*DIM threads
    int node = gid >> 7, d = gid & 127;
    const float* coords = cvt + OFF_COORDS;
    const float* w0     = cvt + OFF_EW0;
    const float* b0     = cvt + OFF_EB0;
    float c0 = coords[node*2+0], c1 = coords[node*2+1];
    float v  = fmaf(c0, w0[d], fmaf(c1, w0[DIM+d], b0[d]));
    h0[gid]  = v > 0.f ? v : 0.f;
}

// ------------- fp32 GEMM: out[M,NCOLS] = A[M,128] @ W[128,NCOLS] (+bias) -----------
// block 256, tile 32 rows x 64 cols; grid = (M/32, NCOLS/64); LDS 48 KB
template<int NCOLS>
__global__ __launch_bounds__(256) void gemm32_k(const float* __restrict__ A,
    const float* __restrict__ W, const float* __restrict__ bias, float* __restrict__ out)
{
    __shared__ __align__(16) float sW[128*64];   // [k][cc] 32 KB
    __shared__ __align__(16) float sA[32*128];   // [r][k]  16 KB
    const int rt = blockIdx.x, cb = blockIdx.y, tid = threadIdx.x;

    for (int e = tid; e < 128*64; e += 256){
        int k = e >> 6, cc = e & 63;
        sW[e] = W[k*NCOLS + cb*64 + cc];
    }
    const float4* Ab = (const float4*)(A + (size_t)rt*32*128);
    float4* sA4 = (float4*)sA;
    for (int q = tid; q < 32*32; q += 256) sA4[q] = Ab[q];
    __syncthreads();

    const int cq = tid & 15, rr = tid >> 4;      // cols cq*4.., rows rr & rr+16
    float4 acc0 = make_float4(0.f,0.f,0.f,0.f);
    float4 acc1 = make_float4(0.f,0.f,0.f,0.f);
    for (int kq = 0; kq < 32; ++kq){
        float4 w0 = *(float4*)&sW[(kq*4+0)*64 + cq*4];
        float4 w1 = *(float4*)&sW[(kq*4+1)*64 + cq*4];
        float4 w2 = *(float4*)&sW[(kq*4+2)*64 + cq*4];
        float4 w3 = *(float4*)&sW[(kq*4+3)*64 + cq*4];
        float4 a0 = *(float4*)&sA[rr*128 + kq*4];
        float4 a1 = *(float4*)&sA[(rr+16)*128 + kq*4];
        acc0.x = fmaf(a0.x,w0.x, fmaf(a0.y,w1.x, fmaf(a0.z,w2.x, fmaf(a0.w,w3.x, acc0.x))));
        acc0.y = fmaf(a0.x,w0.y, fmaf(a0.y,w1.y, fmaf(a0.z,w2.y, fmaf(a0.w,w3.y, acc0.y))));
        acc0.z = fmaf(a0.x,w0.z, fmaf(a0.y,w1.z, fmaf(a0.z,w2.z, fmaf(a0.w,w3.z, acc0.z))));
        acc0.w = fmaf(a0.x,w0.w, fmaf(a0.y,w1.w, fmaf(a0.z,w2.w, fmaf(a0.w,w3.w, acc0.w))));
        acc1.x = fmaf(a1.x,w0.x, fmaf(a1.y,w1.x, fmaf(a1.z,w2.x, fmaf(a1.w,w3.x, acc1.x))));
        acc1.y = fmaf(a1.x,w0.y, fmaf(a1.y,w1.y, fmaf(a1.z,w2.y, fmaf(a1.w,w3.y, acc1.y))));
        acc1.z = fmaf(a1.x,w0.z, fmaf(a1.y,w1.z, fmaf(a1.z,w2.z, fmaf(a1.w,w3.z, acc1.z))));
        acc1.w = fmaf(a1.x,w0.w, fmaf(a1.y,w1.w, fmaf(a1.z,w2.w, fmaf(a1.w,w3.w, acc1.w))));
    }
    const int col0 = cb*64 + cq*4;
    float b0=0.f,b1=0.f,b2=0.f,b3=0.f;
    if (bias){ b0=bias[col0]; b1=bias[col0+1]; b2=bias[col0+2]; b3=bias[col0+3]; }
    int r0 = rt*32 + rr;
    *(float4*)&out[(size_t)r0*NCOLS + col0]      = make_float4(acc0.x+b0, acc0.y+b1, acc0.z+b2, acc0.w+b3);
    *(float4*)&out[(size_t)(r0+16)*NCOLS + col0] = make_float4(acc1.x+b0, acc1.y+b1, acc1.z+b2, acc1.w+b3);
}

// ------------- final projection GEMM, output dtype per flag ------------------------
__global__ __launch_bounds__(256) void gemmout_k(const float* __restrict__ A,
    const float* __restrict__ W, const float* __restrict__ bias,
    void* __restrict__ outp, const float* __restrict__ flag)
{
    __shared__ __align__(16) float sW[128*64];
    __shared__ __align__(16) float sA[32*128];
    const int rt = blockIdx.x, tid = threadIdx.x;
    for (int e = tid; e < 128*64; e += 256){
        int k = e >> 6, cc = e & 63;
        sW[e] = W[k*ODIM + cc];
    }
    const float4* Ab = (const float4*)(A + (size_t)rt*32*128);
    float4* sA4 = (float4*)sA;
    for (int q = tid; q < 32*32; q += 256) sA4[q] = Ab[q];
    __syncthreads();

    const int cq = tid & 15, rr = tid >> 4;
    float4 acc0 = make_float4(0.f,0.f,0.f,0.f);
    float4 acc1 = make_float4(0.f,0.f,0.f,0.f);
    for (int kq = 0; kq < 32; ++kq){
        float4 w0 = *(float4*)&sW[(kq*4+0)*64 + cq*4];
        float4 w1 = *(float4*)&sW[(kq*4+1)*64 + cq*4];
        float4 w2 = *(float4*)&sW[(kq*4+2)*64 + cq*4];
        float4 w3 = *(float4*)&sW[(kq*4+3)*64 + cq*4];
        float4 a0 = *(float4*)&sA[rr*128 + kq*4];
        float4 a1 = *(float4*)&sA[(rr+16)*128 + kq*4];
        acc0.x = fmaf(a0.x,w0.x, fmaf(a0.y,w1.x, fmaf(a0.z,w2.x, fmaf(a0.w,w3.x, acc0.x))));
        acc0.y = fmaf(a0.x,w0.y, fmaf(a0.y,w1.y, fmaf(a0.z,w2.y, fmaf(a0.w,w3.y, acc0.y))));
        acc0.z = fmaf(a0.x,w0.z, fmaf(a0.y,w1.z, fmaf(a0.z,w2.z, fmaf(a0.w,w3.z, acc0.z))));
        acc0.w = fmaf(a0.x,w0.w, fmaf(a0.y,w1.w, fmaf(a0.z,w2.w, fmaf(a0.w,w3.w, acc0.w))));
        acc1.x = fmaf(a1.x,w0.x, fmaf(a1.y,w1.x, fmaf(a1.z,w2.x, fmaf(a1.w,w3.x, acc1.x))));
        acc1.y = fmaf(a1.x,w0.y, fmaf(a1.y,w1.y, fmaf(a1.z,w2.y, fmaf(a1.w,w3.y, acc1.y))));
        acc1.z = fmaf(a1.x,w0.z, fmaf(a1.y,w1.z, fmaf(a1.z,w2.z, fmaf(a1.w,w3.z, acc1.z))));
        acc1.w = fmaf(a1.x,w0.w, fmaf(a1.y,w1.w, fmaf(a1.z,w2.w, fmaf(a1.w,w3.w, acc1.w))));
    }
    const int col0 = cq*4;
    float b0=bias[col0], b1=bias[col0+1], b2=bias[col0+2], b3=bias[col0+3];
    float o0[4] = {acc0.x+b0, acc0.y+b1, acc0.z+b2, acc0.w+b3};
    float o1[4] = {acc1.x+b0, acc1.y+b1, acc1.z+b2, acc1.w+b3};
    int r0 = rt*32 + rr;
    size_t p0 = (size_t)r0*ODIM + col0, p1 = (size_t)(r0+16)*ODIM + col0;
    if (flag[0] != 0.0f){
        bf16* ob = (bf16*)outp;
        #pragma unroll
        for (int i = 0; i < 4; ++i){ ob[p0+i] = __float2bfloat16(o0[i]); ob[p1+i] = __float2bfloat16(o1[i]); }
    } else {
        float* of = (float*)outp;
        *(float4*)&of[p0] = make_float4(o0[0],o0[1],o0[2],o0[3]);
        *(float4*)&of[p1] = make_float4(o1[0],o1[1],o1[2],o1[3]);
    }
}

// ------------- e1 = Wh @ a1, e2 = Wh @ a2 (wave per row) --------------------------
__global__ void e1e2_k(const float* __restrict__ Wh, const float* __restrict__ cvt, int l,
                       float* __restrict__ e1, float* __restrict__ e2)
{
    const float* a1f = cvt + OFF_GA1 + l*DIM;
    const float* a2f = cvt + OFF_GA2 + l*DIM;
    int lane = threadIdx.x & 63;
    int row  = blockIdx.x*4 + (threadIdx.x >> 6);
    const float* w = Wh + (size_t)row*DIM;
    float wlo = w[lane], whi = w[lane+64];
    float s1 = fmaf(wlo, a1f[lane], whi * a1f[lane+64]);
    float s2 = fmaf(wlo, a2f[lane], whi * a2f[lane+64]);
    #pragma unroll
    for (int off = 32; off; off >>= 1){ s1 += __shfl_down(s1, off); s2 += __shfl_down(s2, off); }
    if (lane == 0){ e1[row] = s1; e2[row] = s2; }
}

// ------------- per-batch bitonic sort of e2 (2000 -> pad 2048) --------------------
__global__ void sort_k(const float* __restrict__ e2, float* __restrict__ e2s, int* __restrict__ sidx,
                       float* __restrict__ wp, float* __restrict__ wn, float* __restrict__ e2m)
{
    __shared__ float v[2048];
    __shared__ int  ix[2048];
    const int b = blockIdx.x, t = threadIdx.x;   // 1024 threads
    for (int i = t; i < 2048; i += 1024){
        v[i]  = (i < NNODE) ? e2[b*NNODE + i] : 3.0e38f;
        ix[i] = i;
    }
    __syncthreads();
    for (int size = 2; size <= 2048; size <<= 1){
        for (int stride = size >> 1; stride > 0; stride >>= 1){
            int i = 2*t - (t & (stride-1));
            int j = i + stride;
            bool asc = ((i & size) == 0);
            float vi = v[i], vj = v[j];
            bool sw = asc ? (vi > vj) : (vi < vj);
            if (sw){ v[i]=vj; v[j]=vi; int tm=ix[i]; ix[i]=ix[j]; ix[j]=tm; }
            __syncthreads();
        }
    }
    float mx = v[NNODE-1];   // pads sort to 2000..2047, so this is the true max
    for (int i = t; i < NNODE; i += 1024){
        float val = v[i];
        e2s [b*NNODE+i] = val;
        sidx[b*NNODE+i] = ix[i];
        wp  [b*NNODE+i] = __expf(val - mx);          // <= 1
        wn  [b*NNODE+i] = __expf(0.2f*(val - mx));   // <= 1
    }
    if (t == 0) e2m[b] = mx;
}

// ------------- pass A: per-chunk partial sums (vector[D] + scalar) ----------------
// grid = BATCH*CHK = 2000 blocks, 128 threads; 16-row serial loop
__global__ void passA_k(const float* __restrict__ Wh, const int* __restrict__ sidx,
    const float* __restrict__ wp, const float* __restrict__ wn,
    float* __restrict__ chunkP, float* __restrict__ chunkN,
    float* __restrict__ schunkP, float* __restrict__ schunkN)
{
    const int b = blockIdx.x / CHK, c = blockIdx.x % CHK, d = threadIdx.x;
    const int base = b*NNODE;
    float sp=0.f, sn=0.f, ssp=0.f, ssn=0.f;
    #pragma unroll 4
    for (int r = c*CKS; r < c*CKS + CKS; ++r){
        int j = sidx[base + r];
        float whv = Wh[((size_t)base + j)*DIM + d];
        float wpv = wp[base + r], wnv = wn[base + r];
        sp = fmaf(wpv, whv, sp);  sn = fmaf(wnv, whv, sn);
        ssp += wpv;  ssn += wnv;
    }
    const int idx = b*CHK + c;
    chunkP[idx*DIM + d] = sp;
    chunkN[idx*DIM + d] = sn;
    if (d == 0){ schunkP[idx] = ssp; schunkN[idx] = ssn; }
}

// ------------- pass B: cross-chunk suffix (P) / prefix (N) offsets ----------------
// grid = BATCH = 16 blocks, 128 threads; serial 125-step scan (tiny)
__global__ void passB_k(const float* __restrict__ chunkP, const float* __restrict__ chunkN,
    const float* __restrict__ schunkP, const float* __restrict__ schunkN,
    float* __restrict__ offP, float* __restrict__ offN,
    float* __restrict__ soffP, float* __restrict__ soffN)
{
    const int b = blockIdx.x, d = threadIdx.x;
    float accP = 0.f, sAccP = 0.f;
    for (int c = CHK-1; c >= 0; --c){
        int idx = b*CHK + c;
        offP[idx*DIM + d] = accP;
        accP += chunkP[idx*DIM + d];
        if (d == 0){ soffP[idx] = sAccP; sAccP += schunkP[idx]; }
    }
    float accN = 0.f, sAccN = 0.f;
    for (int c = 0; c < CHK; ++c){
        int idx = b*CHK + c;
        offN[idx*DIM + d] = accN;
        accN += chunkN[idx*DIM + d];
        if (d == 0){ soffN[idx] = sAccN; sAccN += schunkN[idx]; }
    }
}

// ------------- pass C: suffix (pos) / prefix (neg) arrays over sorted order -------
// grid = BATCH*CHK = 2000 blocks, 128 threads; 16-row serial loop each direction
__global__ void passC_k(const float* __restrict__ Wh, const int* __restrict__ sidx,
    const float* __restrict__ wp, const float* __restrict__ wn,
    const float* __restrict__ offP, const float* __restrict__ offN,
    const float* __restrict__ soffP, const float* __restrict__ soffN,
    float* __restrict__ Ppos, float* __restrict__ Pneg,
    float* __restrict__ pposs, float* __restrict__ pnegs)
{
    const int b = blockIdx.x / CHK, c = blockIdx.x % CHK, d = threadIdx.x;
    const int base = b*NNODE;
    const size_t pb = (size_t)b*NP1;
    const int idx = b*CHK + c;
    const int r0 = c*CKS, r1 = r0 + CKS;

    if (c == CHK-1){
        Ppos[(pb + NNODE)*DIM + d] = 0.f;
        if (d == 0) pposs[pb + NNODE] = 0.f;
    }
    float pr = offP[idx*DIM + d], spr = soffP[idx];     // suffix sums, descending
    for (int r = r1-1; r >= r0; --r){
        int j = sidx[base + r];
        float whv = Wh[((size_t)base + j)*DIM + d];
        float wpv = wp[base + r];
        pr  = fmaf(wpv, whv, pr);
        spr += wpv;
        Ppos[(pb + r)*DIM + d] = pr;
        if (d == 0) pposs[pb + r] = spr;
    }
    float nr = offN[idx*DIM + d], snr = soffN[idx];     // prefix sums (exclusive)
    for (int r = r0; r < r1; ++r){
        int j = sidx[base + r];
        float whv = Wh[((size_t)base + j)*DIM + d];
        float wnv = wn[base + r];
        Pneg[(pb + r)*DIM + d] = nr;
        if (d == 0) pnegs[pb + r] = snr;
        nr  = fmaf(wnv, whv, nr);
        snr += wnv;
    }
    if (c == CHK-1){
        Pneg[(pb + NNODE)*DIM + d] = nr;
        if (d == 0) pnegs[pb + NNODE] = snr;
    }
}

// ------------- output: h_i = relu((ps*Spos + ns*Sneg)/(ps*zpos + ns*zneg)) --------
__global__ void out_k(const float* __restrict__ e1, const float* __restrict__ e2s,
    const float* __restrict__ e2m, const float* __restrict__ Ppos, const float* __restrict__ Pneg,
    const float* __restrict__ pposs, const float* __restrict__ pnegs, float* __restrict__ h)
{
    const int row = blockIdx.x, d = threadIdx.x;   // 128 threads
    const int b = row / NNODE;
    float e1v = e1[row];
    float s = e1v + e2m[b];
    float m = (s >= 0.f) ? s : 0.2f*s;             // = max_j leaky(e1_i + e2_j)
    float ps = __expf(s - m);                      // <= 1
    float ns = __expf(0.2f*s - m);                 // <= 1
    const float* es = e2s + b*NNODE;
    float t = -e1v;
    int lo = 0, hi = NNODE;                        // first k with es[k] >= t
    while (lo < hi){ int mid = (lo+hi) >> 1; if (es[mid] < t) lo = mid+1; else hi = mid; }
    size_t kb = (size_t)b*NP1 + lo;
    float numer = ps*Ppos[kb*DIM + d] + ns*Pneg[kb*DIM + d];
    float Z     = ps*pposs[kb]        + ns*pnegs[kb];       // > 0
    float q = numer / Z;
    h[(size_t)row*DIM + d] = (q > 0.f) ? q : ((q == q) ? 0.f : q);
}

extern "C" void kernel_launch(void* const* d_in, const int* in_sizes, int n_in,
                              void* d_out, int out_size, void* d_ws, size_t ws_size,
                              hipStream_t stream)
{
    (void)in_sizes; (void)n_in; (void)out_size; (void)ws_size;

    float* f = (float*)d_ws;
    float* flag    = f;  f += 4;
    float* cvt     = f;  f += CVT_TOT;                 // 0.56 MB
    float* h       = f;  f += (size_t)BN*DIM;          // 16.4 MB
    float* Wh      = f;  f += (size_t)BN*DIM;          // 16.4 MB
    float* Ppos    = f;  f += (size_t)BATCH*NP1*DIM;   // 16.4 MB
    float* Pneg    = f;  f += (size_t)BATCH*NP1*DIM;   // 16.4 MB
    float* chunkP  = f;  f += BATCH*CHK*DIM;           // 1 MB
    float* chunkN  = f;  f += BATCH*CHK*DIM;           // 1 MB
    float* offP    = f;  f += BATCH*CHK*DIM;           // 1 MB
    float* offN    = f;  f += BATCH*CHK*DIM;           // 1 MB
    float* schunkP = f;  f += BATCH*CHK;
    float* schunkN = f;  f += BATCH*CHK;
    float* soffP   = f;  f += BATCH*CHK;
    float* soffN   = f;  f += BATCH*CHK;
    float* e1      = f;  f += BN;
    float* e2      = f;  f += BN;
    float* e2s     = f;  f += BN;
    float* wp      = f;  f += BN;
    float* wn      = f;  f += BN;
    float* pposs   = f;  f += BATCH*NP1;
    float* pnegs   = f;  f += BATCH*NP1;
    float* e2m     = f;  f += 16;
    int*   sidx    = (int*)f;

    // 1. dtype sniff + convert all inputs to fp32 (single launch)
    sniff_k<<<1, 256, 0, stream>>>((const unsigned short*)d_in[0], flag);
    InPtrs ip;
    for (int i = 0; i < 10; ++i) ip.p[i] = d_in[i];
    convert_all_k<<<(CVT_TOT+255)/256, 256, 0, stream>>>(ip, cvt, flag);

    // 2. encoder: h0 = relu(coords@w0+b0) -> Wh buffer; h = h0@w1 + b1
    enc0_k<<<BN*DIM/256, 256, 0, stream>>>(cvt, Wh);
    gemm32_k<DIM><<<dim3(BN/32, 2), 256, 0, stream>>>(Wh, cvt + OFF_EW1, cvt + OFF_EB1, h);

    // 3. GAT layers (exact separable-softmax factorization)
    for (int l = 0; l < NLAYER; ++l){
        gemm32_k<DIM><<<dim3(BN/32, 2), 256, 0, stream>>>(h, cvt + OFF_GW + l*DIM*DIM, nullptr, Wh);
        e1e2_k<<<BN/4, 256, 0, stream>>>(Wh, cvt, l, e1, e2);
        sort_k<<<BATCH, 1024, 0, stream>>>(e2, e2s, sidx, wp, wn, e2m);
        passA_k<<<BATCH*CHK, DIM, 0, stream>>>(Wh, sidx, wp, wn, chunkP, chunkN, schunkP, schunkN);
        passB_k<<<BATCH, DIM, 0, stream>>>(chunkP, chunkN, schunkP, schunkN, offP, offN, soffP, soffN);
        passC_k<<<BATCH*CHK, DIM, 0, stream>>>(Wh, sidx, wp, wn, offP, offN, soffP, soffN,
                                               Ppos, Pneg, pposs, pnegs);
        out_k<<<BN, DIM, 0, stream>>>(e1, e2s, e2m, Ppos, Pneg, pposs, pnegs, h);
    }

    // 4. projection, output dtype per flag
    gemmout_k<<<BN/32, 256, 0, stream>>>(h, cvt + OFF_PW, cvt + OFF_PB, d_out, flag);
}

// Round 4
// 424.931 us; speedup vs baseline: 1.3928x; 1.3163x over previous
//
#include <hip/hip_runtime.h>
#include <hip/hip_bf16.h>

using bf16 = __hip_bfloat16;

#define BATCH 16
#define NNODE 2000
#define DIM   128
#define ODIM  64
#define NLAYER 3
#define BN    (BATCH*NNODE)   // 32000
#define NP1   (NNODE+1)       // 2001
#define CHK   125             // chunks per batch
#define CKS   16              // chunk size (125*16 = 2000)

// converted-input element offsets inside cvt buffer
#define OFF_COORDS 0
#define OFF_EW0    64000
#define OFF_EB0    64256
#define OFF_EW1    64384
#define OFF_EB1    80768
#define OFF_GW     80896
#define OFF_GA1    130048
#define OFF_GA2    130432
#define OFF_PW     130816
#define OFF_PB     139008
#define CVT_TOT    139072

// ------------- dtype sniff: bf16 storage => even halfwords all have sane exponent ----
__global__ void sniff_k(const unsigned short* __restrict__ raw, float* __restrict__ flag)
{
    __shared__ int cnt[256];
    int t = threadIdx.x, c = 0;
    for (int k = t; k < 2048; k += 256){
        unsigned short u = raw[2*k];          // even halfwords (8 KB touched, safe)
        int e = (u >> 7) & 0xFF;
        if (e >= 100 && e <= 140) ++c;
    }
    cnt[t] = c;
    __syncthreads();
    for (int s = 128; s; s >>= 1){ if (t < s) cnt[t] += cnt[t+s]; __syncthreads(); }
    if (t == 0) flag[0] = (cnt[0] >= 1800) ? 1.0f : 0.0f;   // 1 => bf16 storage
}

// ------------- convert ALL inputs to fp32 scratch in one launch --------------------
struct InPtrs { const void* p[10]; };

__global__ void convert_all_k(InPtrs in, float* __restrict__ dst, const float* __restrict__ flag)
{
    const int off[11] = {OFF_COORDS,OFF_EW0,OFF_EB0,OFF_EW1,OFF_EB1,
                         OFF_GW,OFF_GA1,OFF_GA2,OFF_PW,OFF_PB,CVT_TOT};
    int i = blockIdx.x*256 + threadIdx.x;
    if (i >= CVT_TOT) return;
    int seg = 0;
    #pragma unroll
    for (int s = 1; s < 10; ++s) if (i >= off[s]) seg = s;
    int li = i - off[seg];
    if (flag[0] != 0.0f) dst[i] = __bfloat162float(((const bf16*)in.p[seg])[li]);
    else                 dst[i] = ((const float*)in.p[seg])[li];
}

// ------------- encoder layer 0: h0 = relu(coords @ w0 + b0) ------------------------
__global__ void enc0_k(const float* __restrict__ cvt, float* __restrict__ h0)
{
    int gid  = blockIdx.x*256 + threadIdx.x;       // BN*DIM threads
    int node = gid >> 7, d = gid & 127;
    const float* coords = cvt + OFF_COORDS;
    const float* w0     = cvt + OFF_EW0;
    const float* b0     = cvt + OFF_EB0;
    float c0 = coords[node*2+0], c1 = coords[node*2+1];
    float v  = fmaf(c0, w0[d], fmaf(c1, w0[DIM+d], b0[d]));
    h0[gid]  = v > 0.f ? v : 0.f;
}

// ------------- fp32 GEMM: out[M,NCOLS] = A[M,128] @ W[128,NCOLS] (+bias) -----------
// block 256, tile 32 rows x 64 cols; grid = (M/32, NCOLS/64); LDS 48 KB
template<int NCOLS>
__global__ __launch_bounds__(256) void gemm32_k(const float* __restrict__ A,
    const float* __restrict__ W, const float* __restrict__ bias, float* __restrict__ out)
{
    __shared__ __align__(16) float sW[128*64];   // [k][cc] 32 KB
    __shared__ __align__(16) float sA[32*128];   // [r][k]  16 KB
    const int rt = blockIdx.x, cb = blockIdx.y, tid = threadIdx.x;

    for (int e = tid; e < 128*64; e += 256){
        int k = e >> 6, cc = e & 63;
        sW[e] = W[k*NCOLS + cb*64 + cc];
    }
    const float4* Ab = (const float4*)(A + (size_t)rt*32*128);
    float4* sA4 = (float4*)sA;
    for (int q = tid; q < 32*32; q += 256) sA4[q] = Ab[q];
    __syncthreads();

    const int cq = tid & 15, rr = tid >> 4;      // cols cq*4.., rows rr & rr+16
    float4 acc0 = make_float4(0.f,0.f,0.f,0.f);
    float4 acc1 = make_float4(0.f,0.f,0.f,0.f);
    for (int kq = 0; kq < 32; ++kq){
        float4 w0 = *(float4*)&sW[(kq*4+0)*64 + cq*4];
        float4 w1 = *(float4*)&sW[(kq*4+1)*64 + cq*4];
        float4 w2 = *(float4*)&sW[(kq*4+2)*64 + cq*4];
        float4 w3 = *(float4*)&sW[(kq*4+3)*64 + cq*4];
        float4 a0 = *(float4*)&sA[rr*128 + kq*4];
        float4 a1 = *(float4*)&sA[(rr+16)*128 + kq*4];
        acc0.x = fmaf(a0.x,w0.x, fmaf(a0.y,w1.x, fmaf(a0.z,w2.x, fmaf(a0.w,w3.x, acc0.x))));
        acc0.y = fmaf(a0.x,w0.y, fmaf(a0.y,w1.y, fmaf(a0.z,w2.y, fmaf(a0.w,w3.y, acc0.y))));
        acc0.z = fmaf(a0.x,w0.z, fmaf(a0.y,w1.z, fmaf(a0.z,w2.z, fmaf(a0.w,w3.z, acc0.z))));
        acc0.w = fmaf(a0.x,w0.w, fmaf(a0.y,w1.w, fmaf(a0.z,w2.w, fmaf(a0.w,w3.w, acc0.w))));
        acc1.x = fmaf(a1.x,w0.x, fmaf(a1.y,w1.x, fmaf(a1.z,w2.x, fmaf(a1.w,w3.x, acc1.x))));
        acc1.y = fmaf(a1.x,w0.y, fmaf(a1.y,w1.y, fmaf(a1.z,w2.y, fmaf(a1.w,w3.y, acc1.y))));
        acc1.z = fmaf(a1.x,w0.z, fmaf(a1.y,w1.z, fmaf(a1.z,w2.z, fmaf(a1.w,w3.z, acc1.z))));
        acc1.w = fmaf(a1.x,w0.w, fmaf(a1.y,w1.w, fmaf(a1.z,w2.w, fmaf(a1.w,w3.w, acc1.w))));
    }
    const int col0 = cb*64 + cq*4;
    float b0=0.f,b1=0.f,b2=0.f,b3=0.f;
    if (bias){ b0=bias[col0]; b1=bias[col0+1]; b2=bias[col0+2]; b3=bias[col0+3]; }
    int r0 = rt*32 + rr;
    *(float4*)&out[(size_t)r0*NCOLS + col0]      = make_float4(acc0.x+b0, acc0.y+b1, acc0.z+b2, acc0.w+b3);
    *(float4*)&out[(size_t)(r0+16)*NCOLS + col0] = make_float4(acc1.x+b0, acc1.y+b1, acc1.z+b2, acc1.w+b3);
}

// ------------- final projection GEMM, output dtype per flag ------------------------
__global__ __launch_bounds__(256) void gemmout_k(const float* __restrict__ A,
    const float* __restrict__ W, const float* __restrict__ bias,
    void* __restrict__ outp, const float* __restrict__ flag)
{
    __shared__ __align__(16) float sW[128*64];
    __shared__ __align__(16) float sA[32*128];
    const int rt = blockIdx.x, tid = threadIdx.x;
    for (int e = tid; e < 128*64; e += 256){
        int k = e >> 6, cc = e & 63;
        sW[e] = W[k*ODIM + cc];
    }
    const float4* Ab = (const float4*)(A + (size_t)rt*32*128);
    float4* sA4 = (float4*)sA;
    for (int q = tid; q < 32*32; q += 256) sA4[q] = Ab[q];
    __syncthreads();

    const int cq = tid & 15, rr = tid >> 4;
    float4 acc0 = make_float4(0.f,0.f,0.f,0.f);
    float4 acc1 = make_float4(0.f,0.f,0.f,0.f);
    for (int kq = 0; kq < 32; ++kq){
        float4 w0 = *(float4*)&sW[(kq*4+0)*64 + cq*4];
        float4 w1 = *(float4*)&sW[(kq*4+1)*64 + cq*4];
        float4 w2 = *(float4*)&sW[(kq*4+2)*64 + cq*4];
        float4 w3 = *(float4*)&sW[(kq*4+3)*64 + cq*4];
        float4 a0 = *(float4*)&sA[rr*128 + kq*4];
        float4 a1 = *(float4*)&sA[(rr+16)*128 + kq*4];
        acc0.x = fmaf(a0.x,w0.x, fmaf(a0.y,w1.x, fmaf(a0.z,w2.x, fmaf(a0.w,w3.x, acc0.x))));
        acc0.y = fmaf(a0.x,w0.y, fmaf(a0.y,w1.y, fmaf(a0.z,w2.y, fmaf(a0.w,w3.y, acc0.y))));
        acc0.z = fmaf(a0.x,w0.z, fmaf(a0.y,w1.z, fmaf(a0.z,w2.z, fmaf(a0.w,w3.z, acc0.z))));
        acc0.w = fmaf(a0.x,w0.w, fmaf(a0.y,w1.w, fmaf(a0.z,w2.w, fmaf(a0.w,w3.w, acc0.w))));
        acc1.x = fmaf(a1.x,w0.x, fmaf(a1.y,w1.x, fmaf(a1.z,w2.x, fmaf(a1.w,w3.x, acc1.x))));
        acc1.y = fmaf(a1.x,w0.y, fmaf(a1.y,w1.y, fmaf(a1.z,w2.y, fmaf(a1.w,w3.y, acc1.y))));
        acc1.z = fmaf(a1.x,w0.z, fmaf(a1.y,w1.z, fmaf(a1.z,w2.z, fmaf(a1.w,w3.z, acc1.z))));
        acc1.w = fmaf(a1.x,w0.w, fmaf(a1.y,w1.w, fmaf(a1.z,w2.w, fmaf(a1.w,w3.w, acc1.w))));
    }
    const int col0 = cq*4;
    float b0=bias[col0], b1=bias[col0+1], b2=bias[col0+2], b3=bias[col0+3];
    float o0[4] = {acc0.x+b0, acc0.y+b1, acc0.z+b2, acc0.w+b3};
    float o1[4] = {acc1.x+b0, acc1.y+b1, acc1.z+b2, acc1.w+b3};
    int r0 = rt*32 + rr;
    size_t p0 = (size_t)r0*ODIM + col0, p1 = (size_t)(r0+16)*ODIM + col0;
    if (flag[0] != 0.0f){
        bf16* ob = (bf16*)outp;
        #pragma unroll
        for (int i = 0; i < 4; ++i){ ob[p0+i] = __float2bfloat16(o0[i]); ob[p1+i] = __float2bfloat16(o1[i]); }
    } else {
        float* of = (float*)outp;
        *(float4*)&of[p0] = make_float4(o0[0],o0[1],o0[2],o0[3]);
        *(float4*)&of[p1] = make_float4(o1[0],o1[1],o1[2],o1[3]);
    }
}

// ------------- e1 = Wh @ a1, e2 = Wh @ a2 (wave per row) --------------------------
__global__ void e1e2_k(const float* __restrict__ Wh, const float* __restrict__ cvt, int l,
                       float* __restrict__ e1, float* __restrict__ e2)
{
    const float* a1f = cvt + OFF_GA1 + l*DIM;
    const float* a2f = cvt + OFF_GA2 + l*DIM;
    int lane = threadIdx.x & 63;
    int row  = blockIdx.x*4 + (threadIdx.x >> 6);
    const float* w = Wh + (size_t)row*DIM;
    float wlo = w[lane], whi = w[lane+64];
    float s1 = fmaf(wlo, a1f[lane], whi * a1f[lane+64]);
    float s2 = fmaf(wlo, a2f[lane], whi * a2f[lane+64]);
    #pragma unroll
    for (int off = 32; off; off >>= 1){ s1 += __shfl_down(s1, off); s2 += __shfl_down(s2, off); }
    if (lane == 0){ e1[row] = s1; e2[row] = s2; }
}

// ------------- per-batch bitonic sort of e2 (2000 -> pad 2048) --------------------
__global__ void sort_k(const float* __restrict__ e2, float* __restrict__ e2s, int* __restrict__ sidx,
                       float* __restrict__ wp, float* __restrict__ wn, float* __restrict__ e2m)
{
    __shared__ float v[2048];
    __shared__ int  ix[2048];
    const int b = blockIdx.x, t = threadIdx.x;   // 1024 threads
    for (int i = t; i < 2048; i += 1024){
        v[i]  = (i < NNODE) ? e2[b*NNODE + i] : 3.0e38f;
        ix[i] = i;
    }
    __syncthreads();
    for (int size = 2; size <= 2048; size <<= 1){
        for (int stride = size >> 1; stride > 0; stride >>= 1){
            int i = 2*t - (t & (stride-1));
            int j = i + stride;
            bool asc = ((i & size) == 0);
            float vi = v[i], vj = v[j];
            bool sw = asc ? (vi > vj) : (vi < vj);
            if (sw){ v[i]=vj; v[j]=vi; int tm=ix[i]; ix[i]=ix[j]; ix[j]=tm; }
            __syncthreads();
        }
    }
    float mx = v[NNODE-1];   // pads sort to 2000..2047, so this is the true max
    for (int i = t; i < NNODE; i += 1024){
        float val = v[i];
        e2s [b*NNODE+i] = val;
        sidx[b*NNODE+i] = ix[i];
        wp  [b*NNODE+i] = __expf(val - mx);          // <= 1
        wn  [b*NNODE+i] = __expf(0.2f*(val - mx));   // <= 1
    }
    if (t == 0) e2m[b] = mx;
}

// ------------- pass A: per-chunk partial sums (vector[D] + scalar) ----------------
// grid = BATCH*CHK = 2000 blocks, 128 threads; 16-row serial loop
__global__ void passA_k(const float* __restrict__ Wh, const int* __restrict__ sidx,
    const float* __restrict__ wp, const float* __restrict__ wn,
    float* __restrict__ chunkP, float* __restrict__ chunkN,
    float* __restrict__ schunkP, float* __restrict__ schunkN)
{
    const int b = blockIdx.x / CHK, c = blockIdx.x % CHK, d = threadIdx.x;
    const int base = b*NNODE;
    float sp=0.f, sn=0.f, ssp=0.f, ssn=0.f;
    #pragma unroll 4
    for (int r = c*CKS; r < c*CKS + CKS; ++r){
        int j = sidx[base + r];
        float whv = Wh[((size_t)base + j)*DIM + d];
        float wpv = wp[base + r], wnv = wn[base + r];
        sp = fmaf(wpv, whv, sp);  sn = fmaf(wnv, whv, sn);
        ssp += wpv;  ssn += wnv;
    }
    const int idx = b*CHK + c;
    chunkP[idx*DIM + d] = sp;
    chunkN[idx*DIM + d] = sn;
    if (d == 0){ schunkP[idx] = ssp; schunkN[idx] = ssn; }
}

// ------------- pass B: cross-chunk suffix (P) / prefix (N) offsets ----------------
// grid = (BATCH, 2); block = 256. blockIdx.y==0 -> P suffix, ==1 -> N prefix.
// Threads 0..127 (waves 0-1): vector scan, register-tiled (25 independent loads/tile).
// Thread 128 (wave 2): scalar scan, same tiling — runs concurrently with waves 0-1.
__global__ __launch_bounds__(256) void passB_k(
    const float* __restrict__ chunkP, const float* __restrict__ chunkN,
    const float* __restrict__ schunkP, const float* __restrict__ schunkN,
    float* __restrict__ offP, float* __restrict__ offN,
    float* __restrict__ soffP, float* __restrict__ soffN)
{
    const int b = blockIdx.x, tid = threadIdx.x;
    const bool doP = (blockIdx.y == 0);
    const float* chunk  = doP ? chunkP  : chunkN;
    const float* schunk = doP ? schunkP : schunkN;
    float* off  = doP ? offP  : offN;
    float* soff = doP ? soffP : soffN;

    if (tid < 128){
        const int d = tid;
        float acc = 0.f, v[25];
        #pragma unroll
        for (int t = 0; t < 5; ++t){
            const int c0 = doP ? (4-t)*25 : t*25;
            #pragma unroll
            for (int k = 0; k < 25; ++k) v[k] = chunk[(b*CHK + c0 + k)*DIM + d];
            if (doP){
                #pragma unroll
                for (int k = 24; k >= 0; --k){ off[(b*CHK + c0 + k)*DIM + d] = acc; acc += v[k]; }
            } else {
                #pragma unroll
                for (int k = 0; k < 25; ++k){ off[(b*CHK + c0 + k)*DIM + d] = acc; acc += v[k]; }
            }
        }
    } else if (tid == 128){
        float sacc = 0.f, sv[25];
        #pragma unroll
        for (int t = 0; t < 5; ++t){
            const int c0 = doP ? (4-t)*25 : t*25;
            #pragma unroll
            for (int k = 0; k < 25; ++k) sv[k] = schunk[b*CHK + c0 + k];
            if (doP){
                #pragma unroll
                for (int k = 24; k >= 0; --k){ soff[b*CHK + c0 + k] = sacc; sacc += sv[k]; }
            } else {
                #pragma unroll
                for (int k = 0; k < 25; ++k){ soff[b*CHK + c0 + k] = sacc; sacc += sv[k]; }
            }
        }
    }
}

// ------------- pass C: suffix (pos) / prefix (neg) arrays over sorted order -------
// grid = BATCH*CHK = 2000 blocks, 128 threads; 16-row serial loop each direction
__global__ void passC_k(const float* __restrict__ Wh, const int* __restrict__ sidx,
    const float* __restrict__ wp, const float* __restrict__ wn,
    const float* __restrict__ offP, const float* __restrict__ offN,
    const float* __restrict__ soffP, const float* __restrict__ soffN,
    float* __restrict__ Ppos, float* __restrict__ Pneg,
    float* __restrict__ pposs, float* __restrict__ pnegs)
{
    const int b = blockIdx.x / CHK, c = blockIdx.x % CHK, d = threadIdx.x;
    const int base = b*NNODE;
    const size_t pb = (size_t)b*NP1;
    const int idx = b*CHK + c;
    const int r0 = c*CKS, r1 = r0 + CKS;

    if (c == CHK-1){
        Ppos[(pb + NNODE)*DIM + d] = 0.f;
        if (d == 0) pposs[pb + NNODE] = 0.f;
    }
    float pr = offP[idx*DIM + d], spr = soffP[idx];     // suffix sums, descending
    for (int r = r1-1; r >= r0; --r){
        int j = sidx[base + r];
        float whv = Wh[((size_t)base + j)*DIM + d];
        float wpv = wp[base + r];
        pr  = fmaf(wpv, whv, pr);
        spr += wpv;
        Ppos[(pb + r)*DIM + d] = pr;
        if (d == 0) pposs[pb + r] = spr;
    }
    float nr = offN[idx*DIM + d], snr = soffN[idx];     // prefix sums (exclusive)
    for (int r = r0; r < r1; ++r){
        int j = sidx[base + r];
        float whv = Wh[((size_t)base + j)*DIM + d];
        float wnv = wn[base + r];
        Pneg[(pb + r)*DIM + d] = nr;
        if (d == 0) pnegs[pb + r] = snr;
        nr  = fmaf(wnv, whv, nr);
        snr += wnv;
    }
    if (c == CHK-1){
        Pneg[(pb + NNODE)*DIM + d] = nr;
        if (d == 0) pnegs[pb + NNODE] = snr;
    }
}

// ------------- output: h_i = relu((ps*Spos + ns*Sneg)/(ps*zpos + ns*zneg)) --------
__global__ void out_k(const float* __restrict__ e1, const float* __restrict__ e2s,
    const float* __restrict__ e2m, const float* __restrict__ Ppos, const float* __restrict__ Pneg,
    const float* __restrict__ pposs, const float* __restrict__ pnegs, float* __restrict__ h)
{
    const int row = blockIdx.x, d = threadIdx.x;   // 128 threads
    const int b = row / NNODE;
    float e1v = e1[row];
    float s = e1v + e2m[b];
    float m = (s >= 0.f) ? s : 0.2f*s;             // = max_j leaky(e1_i + e2_j)
    float ps = __expf(s - m);                      // <= 1
    float ns = __expf(0.2f*s - m);                 // <= 1
    const float* es = e2s + b*NNODE;
    float t = -e1v;
    int lo = 0, hi = NNODE;                        // first k with es[k] >= t
    while (lo < hi){ int mid = (lo+hi) >> 1; if (es[mid] < t) lo = mid+1; else hi = mid; }
    size_t kb = (size_t)b*NP1 + lo;
    float numer = ps*Ppos[kb*DIM + d] + ns*Pneg[kb*DIM + d];
    float Z     = ps*pposs[kb]        + ns*pnegs[kb];       // > 0
    float q = numer / Z;
    h[(size_t)row*DIM + d] = (q > 0.f) ? q : ((q == q) ? 0.f : q);
}

extern "C" void kernel_launch(void* const* d_in, const int* in_sizes, int n_in,
                              void* d_out, int out_size, void* d_ws, size_t ws_size,
                              hipStream_t stream)
{
    (void)in_sizes; (void)n_in; (void)out_size; (void)ws_size;

    float* f = (float*)d_ws;
    float* flag    = f;  f += 4;
    float* cvt     = f;  f += CVT_TOT;                 // 0.56 MB
    float* h       = f;  f += (size_t)BN*DIM;          // 16.4 MB
    float* Wh      = f;  f += (size_t)BN*DIM;          // 16.4 MB
    float* Ppos    = f;  f += (size_t)BATCH*NP1*DIM;   // 16.4 MB
    float* Pneg    = f;  f += (size_t)BATCH*NP1*DIM;   // 16.4 MB
    float* chunkP  = f;  f += BATCH*CHK*DIM;           // 1 MB
    float* chunkN  = f;  f += BATCH*CHK*DIM;           // 1 MB
    float* offP    = f;  f += BATCH*CHK*DIM;           // 1 MB
    float* offN    = f;  f += BATCH*CHK*DIM;           // 1 MB
    float* schunkP = f;  f += BATCH*CHK;
    float* schunkN = f;  f += BATCH*CHK;
    float* soffP   = f;  f += BATCH*CHK;
    float* soffN   = f;  f += BATCH*CHK;
    float* e1      = f;  f += BN;
    float* e2      = f;  f += BN;
    float* e2s     = f;  f += BN;
    float* wp      = f;  f += BN;
    float* wn      = f;  f += BN;
    float* pposs   = f;  f += BATCH*NP1;
    float* pnegs   = f;  f += BATCH*NP1;
    float* e2m     = f;  f += 16;
    int*   sidx    = (int*)f;

    // 1. dtype sniff + convert all inputs to fp32 (single launch)
    sniff_k<<<1, 256, 0, stream>>>((const unsigned short*)d_in[0], flag);
    InPtrs ip;
    for (int i = 0; i < 10; ++i) ip.p[i] = d_in[i];
    convert_all_k<<<(CVT_TOT+255)/256, 256, 0, stream>>>(ip, cvt, flag);

    // 2. encoder: h0 = relu(coords@w0+b0) -> Wh buffer; h = h0@w1 + b1
    enc0_k<<<BN*DIM/256, 256, 0, stream>>>(cvt, Wh);
    gemm32_k<DIM><<<dim3(BN/32, 2), 256, 0, stream>>>(Wh, cvt + OFF_EW1, cvt + OFF_EB1, h);

    // 3. GAT layers (exact separable-softmax factorization)
    for (int l = 0; l < NLAYER; ++l){
        gemm32_k<DIM><<<dim3(BN/32, 2), 256, 0, stream>>>(h, cvt + OFF_GW + l*DIM*DIM, nullptr, Wh);
        e1e2_k<<<BN/4, 256, 0, stream>>>(Wh, cvt, l, e1, e2);
        sort_k<<<BATCH, 1024, 0, stream>>>(e2, e2s, sidx, wp, wn, e2m);
        passA_k<<<BATCH*CHK, DIM, 0, stream>>>(Wh, sidx, wp, wn, chunkP, chunkN, schunkP, schunkN);
        passB_k<<<dim3(BATCH, 2), 256, 0, stream>>>(chunkP, chunkN, schunkP, schunkN,
                                                    offP, offN, soffP, soffN);
        passC_k<<<BATCH*CHK, DIM, 0, stream>>>(Wh, sidx, wp, wn, offP, offN, soffP, soffN,
                                               Ppos, Pneg, pposs, pnegs);
        out_k<<<BN, DIM, 0, stream>>>(e1, e2s, e2m, Ppos, Pneg, pposs, pnegs, h);
    }

    // 4. projection, output dtype per flag
    gemmout_k<<<BN/32, 256, 0, stream>>>(h, cvt + OFF_PW, cvt + OFF_PB, d_out, flag);
}